// Round 8
// baseline (21081.218 us; speedup 1.0000x reference)
//
#include <hip/hip_runtime.h>
#include <math.h>

// Problem constants (fixed by the reference)
#define B_  32
#define C_  64
#define T_  2048
#define H_  1024

// Recurrence decomposition: 16 groups x 2 batches; 16 WGs (slices) per group
#define NGROUP 16
#define BPG    2
#define NSLICE 16
#define ROWS   64                    // H / NSLICE
#define NWG    (NGROUP * NSLICE)     // 256 WGs == 256 CUs, 1/CU -> co-resident
#define NTHR   512
#define CHUNK  66                    // padded LDS chunk stride (r7: conflicts -> 0)

// d_ws layout:
//   [0, 4096)      : unsigned cnt[1024]; group g's barrier counter at
//                    cnt[g*32] (128B apart). cnt[512] = sink dump (unused)
//   [4096, ...)    : hbuf, LINE-SPREAD layout: row-quad q (4 consecutive h
//                    floats of one (plane,batch)) lives at float offset
//                    q << QSH. QSH=5 -> one 128B line per quad (2 MB total);
//                    QSH=2 -> dense fallback (= round-6 layout, 256 KB).

__global__ void esn_init_kernel(unsigned* cnt, unsigned* hbuf32, int n) {
    int i = blockIdx.x * blockDim.x + threadIdx.x;
    if (i < 1024) cnt[i] = 0u;
    if (i < n) hbuf32[i] = 0u;
}

// ---------------------------------------------------------------------------
// x_proj[b,h,t] = bias[h] + sum_c x[b,c,t] * W_in[h,c] -> d_out (B,H,T)
// ---------------------------------------------------------------------------
__global__ __launch_bounds__(256) void esn_xproj_kernel(
        const float* __restrict__ x,
        const float* __restrict__ W_in,
        const float* __restrict__ bias,
        float* __restrict__ out) {
    __shared__ float xs[32 * 256];
    const int tid = threadIdx.x;
    const int t0  = blockIdx.x * 256;
    const int h0  = blockIdx.y * 8;
    const int b   = blockIdx.z;
    const float* xb = x + (size_t)b * C_ * T_ + t0;

    float acc[8];
#pragma unroll
    for (int h = 0; h < 8; ++h) acc[h] = 0.0f;

    for (int ch = 0; ch < 2; ++ch) {
        for (int idx = tid; idx < 32 * 64; idx += 256) {
            const int c  = idx >> 6;
            const int t4 = idx & 63;
            float4 v = *(const float4*)(xb + (size_t)(ch * 32 + c) * T_ + t4 * 4);
            *(float4*)(&xs[c * 256 + t4 * 4]) = v;
        }
        __syncthreads();
        for (int c = 0; c < 32; ++c) {
            const float xv = xs[c * 256 + tid];
#pragma unroll
            for (int h = 0; h < 8; ++h)
                acc[h] = fmaf(xv, W_in[(size_t)(h0 + h) * C_ + ch * 32 + c], acc[h]);
        }
        __syncthreads();
    }

    float* ob = out + (size_t)b * H_ * T_ + t0 + tid;
#pragma unroll
    for (int h = 0; h < 8; ++h)
        ob[(size_t)(h0 + h) * T_] = acc[h] + bias[h0 + h];
}

// ---------------------------------------------------------------------------
// Recurrence. WG wg: group g = wg/16 (batches g*2, g*2+1), slice s = wg%16
// (rows s*64..s*64+63). Thread (cg = lane&15, rt = wave*4 + lane/16) holds
// W_res[s*64+rt*2 + {0,1}][cg*64..cg*64+63] in registers across the t-loop
// (no __restrict__ -> in-loop reload illegal under possible aliasing).
//
// Cross-WG exchange via relaxed AGENT-scope atomic RMWs at the LLC (proven
// rounds 5/6: no fences, no wbl2/inv). Round-8 change: hbuf is LINE-SPREAD —
// each row-quad on its own 128B line (QSH=5), cutting per-line RMW count
// 272 -> 34 (round-7 evidence: LLC serializes same-line atomics; round 6's
// 3.23us/step matched ~270 x ~30cy line-lock arithmetic).
// ---------------------------------------------------------------------------
template <int QSH>
__global__ __launch_bounds__(NTHR, 2) void esn_recur_kernel(
        const float* W_res,
        float* out,
        unsigned* cnt,
        float* hbuf) {
    const int wg   = blockIdx.x;
    const int g    = wg >> 4;
    const int s    = wg & 15;
    const int tid  = threadIdx.x;
    const int wave = tid >> 6;
    const int lane = tid & 63;
    const int cg   = lane & 15;                 // col-group: cols cg*64..+63
    const int rt   = (wave << 2) + (lane >> 4); // 0..31 row-pair index
    const int row0 = s * ROWS + rt * 2;
    const int b0   = g * BPG;

    unsigned long long* hb64 = (unsigned long long*)hbuf;

    // ---- persistent register weights: 2 rows x 16 float4 ----
    float4 w0[16], w1[16];
    {
        const float4* p0 = (const float4*)(W_res + (size_t)row0 * H_) + (cg << 4);
        const float4* p1 = (const float4*)(W_res + (size_t)(row0 + 1) * H_) + (cg << 4);
#pragma unroll
        for (int k = 0; k < 16; ++k) { w0[k] = p0[k]; w1[k] = p1[k]; }
    }

    // h tiles in LDS, padded chunks: col c of batch b at hl[b][(c/64)*66 + c%64]
    __shared__ __align__(16) float hl[BPG][16 * CHUNK];

    // h-fill role: thread loads row-quad fc..fc+3 of batch fb (2 u64 RMWs,
    // both u64s within quad's private line)
    const int fb = tid >> 8;                 // batch 0/1
    const int fc = (tid << 2) & 1023;        // row base (multiple of 4)
    float* hlw = &hl[fb][(fc >> 6) * CHUNK + (fc & 63)];

    // finalize role: lanes cg<2 own batch b0+cg, rows (row0, row0+1)
    const bool fin  = (cg < BPG);
    const int  fbat = cg;                    // 0/1 (valid when fin)
    float* op0 = out + ((size_t)(b0 + (fin ? fbat : 0)) * H_ + row0) * (size_t)T_;
    float* op1 = op0 + T_;                   // next row, same batch

    float xp0 = fin ? op0[0] : 0.0f;         // x_proj for step 0
    float xp1 = fin ? op1[0] : 0.0f;
    float hprev0 = 0.0f, hprev1 = 0.0f;      // own rows' exact f32 state

    unsigned long long sink = 0ull;
    unsigned* grpcnt = &cnt[g * 32];

    // write-side u64 index: quad of row0, slot (row0>>1)&1
    const size_t qw_bat = (size_t)(b0 + (fin ? fbat : 0)) * H_;

    for (int t = 0; t < T_; ++t) {
        const int p = t & 1;

        // (A) h from LLC -> LDS via u64 fetch_add(+0) on the quad's line
        {
            const size_t q   = ((size_t)(p * B_ + b0 + fb) * H_ + fc) >> 2;
            const size_t i64 = q << (QSH - 1);
            unsigned long long q0 = __hip_atomic_fetch_add(
                hb64 + i64, 0ull, __ATOMIC_RELAXED, __HIP_MEMORY_SCOPE_AGENT);
            unsigned long long q1 = __hip_atomic_fetch_add(
                hb64 + i64 + 1, 0ull, __ATOMIC_RELAXED, __HIP_MEMORY_SCOPE_AGENT);
            float4 v = make_float4(__uint_as_float((unsigned)q0),
                                   __uint_as_float((unsigned)(q0 >> 32)),
                                   __uint_as_float((unsigned)q1),
                                   __uint_as_float((unsigned)(q1 >> 32)));
            *(float4*)hlw = v;
        }
        __syncthreads();
        __builtin_amdgcn_sched_barrier(0);

        // prefetch next step's x_proj (plain cached; overlapped with the dot)
        float xp0n = 0.0f, xp1n = 0.0f;
        if (fin && t + 1 < T_) { xp0n = op0[t + 1]; xp1n = op1[t + 1]; }

        // (B) dot: 2 rows x 64 cols x 2 batches, weights from registers
        float s00 = 0.f, s01 = 0.f, s10 = 0.f, s11 = 0.f;  // s[row][batch]
        const float* h0 = &hl[0][cg * CHUNK];
        const float* h1 = &hl[1][cg * CHUNK];
#pragma unroll
        for (int k = 0; k < 16; ++k) {
            const float4 ha  = *(const float4*)(h0 + 4 * k);
            const float4 hb4 = *(const float4*)(h1 + 4 * k);
            const float4 u = w0[k], v = w1[k];
            s00 = fmaf(u.x, ha.x, s00);  s00 = fmaf(u.y, ha.y, s00);
            s00 = fmaf(u.z, ha.z, s00);  s00 = fmaf(u.w, ha.w, s00);
            s10 = fmaf(v.x, ha.x, s10);  s10 = fmaf(v.y, ha.y, s10);
            s10 = fmaf(v.z, ha.z, s10);  s10 = fmaf(v.w, ha.w, s10);
            s01 = fmaf(u.x, hb4.x, s01); s01 = fmaf(u.y, hb4.y, s01);
            s01 = fmaf(u.z, hb4.z, s01); s01 = fmaf(u.w, hb4.w, s01);
            s11 = fmaf(v.x, hb4.x, s11); s11 = fmaf(v.y, hb4.y, s11);
            s11 = fmaf(v.z, hb4.z, s11); s11 = fmaf(v.w, hb4.w, s11);
        }
        // (C) reduce over the 16 cg lanes
#pragma unroll
        for (int m = 1; m <= 8; m <<= 1) {
            s00 += __shfl_xor(s00, m);
            s01 += __shfl_xor(s01, m);
            s10 += __shfl_xor(s10, m);
            s11 += __shfl_xor(s11, m);
        }

        // (D) finalize: lane cg owns batch b0+cg, rows row0 & row0+1
        if (fin) {
            const float sA = fbat ? s01 : s00;   // row0
            const float sB = fbat ? s11 : s10;   // row0+1
            const float pre0 = tanhf(xp0 + sA);
            const float pre1 = tanhf(xp1 + sB);
            const float hn0 = fmaf(0.1f, hprev0, 0.9f * pre0);
            const float hn1 = fmaf(0.1f, hprev1, 0.9f * pre1);
            hprev0 = hn0;
            hprev1 = hn1;
            op0[t] = hn0;                         // plain cached output stores
            op1[t] = hn1;
            const unsigned long long pack =
                ((unsigned long long)__float_as_uint(hn1) << 32) |
                (unsigned long long)__float_as_uint(hn0);
            const size_t qw  = ((size_t)(((t + 1) & 1) * B_) * H_ + qw_bat
                                + (row0 & ~3)) >> 2;
            const size_t i64 = (qw << (QSH - 1)) + ((row0 >> 1) & 1);
            // RETURNING swap (sink keeps sc0): ack => executed at LLC
            sink ^= __hip_atomic_exchange(hb64 + i64, pack,
                                          __ATOMIC_RELAXED,
                                          __HIP_MEMORY_SCOPE_AGENT);
        }
        xp0 = xp0n;
        xp1 = xp1n;

        // (E) fence-free group barrier: monotone LLC counter
        if (t + 1 < T_) {
            __syncthreads();   // vmcnt(0): all swaps executed at LLC
            __builtin_amdgcn_sched_barrier(0);
            if (tid == 0) {
                __hip_atomic_fetch_add(grpcnt, 1u, __ATOMIC_RELAXED,
                                       __HIP_MEMORY_SCOPE_AGENT);
                const unsigned tgt = (unsigned)NSLICE * (unsigned)(t + 1);
                while (__hip_atomic_fetch_add(grpcnt, 0u, __ATOMIC_RELAXED,
                                              __HIP_MEMORY_SCOPE_AGENT) < tgt) {
                    __builtin_amdgcn_s_sleep(1);
                }
            }
            __syncthreads();
            __builtin_amdgcn_sched_barrier(0);
        }
    }

    // keep the swap returns live (forces the returning/sc0 form)
    if (sink == 0x9E3779B97F4A7C15ull && tid == 0) cnt[512] = 1u;
}

extern "C" void kernel_launch(void* const* d_in, const int* in_sizes, int n_in,
                              void* d_out, int out_size, void* d_ws, size_t ws_size,
                              hipStream_t stream) {
    const float* x     = (const float*)d_in[0];   // (B, C, T)
    const float* W_in  = (const float*)d_in[1];   // (H, C)
    const float* W_res = (const float*)d_in[2];   // (H, H)
    const float* bias  = (const float*)d_in[3];   // (H,)
    float* out = (float*)d_out;                   // (B, H, T)

    unsigned* cnt  = (unsigned*)d_ws;
    float*    hbuf = (float*)((char*)d_ws + 4096);

    // quads total = 2 planes * B_ * H_ / 4 = 16384
    const size_t quads = (size_t)2 * B_ * H_ / 4;
    const size_t spread_bytes = 4096 + (quads << 5) * 4;   // 4K + 2 MB
    const bool spread = (ws_size >= spread_bytes);
    const int  n32 = (int)(spread ? (quads << 5) : (quads << 2)); // u32 count

    esn_init_kernel<<<(n32 + 255) / 256, 256, 0, stream>>>(cnt, (unsigned*)hbuf, n32);

    dim3 g1(T_ / 256, H_ / 8, B_);
    esn_xproj_kernel<<<g1, 256, 0, stream>>>(x, W_in, bias, out);

    if (spread)
        esn_recur_kernel<5><<<NWG, NTHR, 0, stream>>>(W_res, out, cnt, hbuf);
    else
        esn_recur_kernel<2><<<NWG, NTHR, 0, stream>>>(W_res, out, cnt, hbuf);
}

// Round 9
// 18586.455 us; speedup vs baseline: 1.1342x; 1.1342x over previous
//
#include <hip/hip_runtime.h>
#include <math.h>

// Problem constants (fixed by the reference)
#define B_  32
#define C_  64
#define T_  2048
#define H_  1024

// Recurrence decomposition: 16 groups x 2 batches; 16 WGs (slices) per group
#define NGROUP 16
#define BPG    2
#define NSLICE 16
#define ROWS   64                    // H / NSLICE
#define NWG    (NGROUP * NSLICE)     // 256 WGs == 256 CUs, 1/CU -> co-resident
#define NTHR   512
#define CHUNK  66                    // padded LDS chunk stride (conflicts = 0, r7/r8)

// d_ws layout:
//   [0, 4096)          : unsigned cnt[1024]:
//                          cnt[g*32]      main barrier counter (one line/group)
//                          cnt[g*32+8]    pre-phase arrival counter
//                          cnt[512+g*16+s] published XCC id (+1) of WG (g,s)
//                          cnt[1000]      sink dump (never actually written)
//   [4096, 4096+256KB) : float hbuf[2][B_][H_] (dense ping-pong h exchange)

__global__ void esn_init_kernel(unsigned* cnt, unsigned* hbuf32) {
    int i = blockIdx.x * blockDim.x + threadIdx.x;
    if (i < 1024) cnt[i] = 0u;
    hbuf32[i] = 0u;   // grid 256x256 = 65536 = 2*B_*H_
}

// ---------------------------------------------------------------------------
// x_proj[b,h,t] = bias[h] + sum_c x[b,c,t] * W_in[h,c] -> d_out (B,H,T)
// ---------------------------------------------------------------------------
__global__ __launch_bounds__(256) void esn_xproj_kernel(
        const float* __restrict__ x,
        const float* __restrict__ W_in,
        const float* __restrict__ bias,
        float* __restrict__ out) {
    __shared__ float xs[32 * 256];
    const int tid = threadIdx.x;
    const int t0  = blockIdx.x * 256;
    const int h0  = blockIdx.y * 8;
    const int b   = blockIdx.z;
    const float* xb = x + (size_t)b * C_ * T_ + t0;

    float acc[8];
#pragma unroll
    for (int h = 0; h < 8; ++h) acc[h] = 0.0f;

    for (int ch = 0; ch < 2; ++ch) {
        for (int idx = tid; idx < 32 * 64; idx += 256) {
            const int c  = idx >> 6;
            const int t4 = idx & 63;
            float4 v = *(const float4*)(xb + (size_t)(ch * 32 + c) * T_ + t4 * 4);
            *(float4*)(&xs[c * 256 + t4 * 4]) = v;
        }
        __syncthreads();
        for (int c = 0; c < 32; ++c) {
            const float xv = xs[c * 256 + tid];
#pragma unroll
            for (int h = 0; h < 8; ++h)
                acc[h] = fmaf(xv, W_in[(size_t)(h0 + h) * C_ + ch * 32 + c], acc[h]);
        }
        __syncthreads();
    }

    float* ob = out + (size_t)b * H_ * T_ + t0 + tid;
#pragma unroll
    for (int h = 0; h < 8; ++h)
        ob[(size_t)(h0 + h) * T_] = acc[h] + bias[h0 + h];
}

// ---------------------------------------------------------------------------
// Recurrence. XCD-affinity swizzle: g=(wg&7)|((wg>>7)<<3), s=(wg>>3)&15 —
// under round-robin dispatch (wg->XCD = wg%8) every group is XCD-pure.
// Pre-phase VERIFIES this via HW_REG_XCC_ID; verdict selects:
//   fast: h reads + barrier polls are relaxed agent atomic LOADS (L1-bypass,
//         served by the shared local TCC where the group's exchanges
//         executed — coherent because same-XCD is verified; loads don't
//         line-lock -> no serialization, no migration).
//   slow: round-6 RMW(fetch_add+0) protocol — correct on any topology.
// Writes stay returning-exchanges in both paths (execute at local TCC).
// Weights: thread (cg,rt) holds W_res[s*64+rt*2+{0,1}][cg*64..+63] in
// registers across the t-loop (no __restrict__ -> reload illegal).
// ---------------------------------------------------------------------------
__global__ __launch_bounds__(NTHR, 2) void esn_recur_kernel(
        const float* W_res,
        float* out,
        unsigned* cnt,
        float* hbuf) {
    const int wg   = blockIdx.x;
    const int g    = (wg & 7) | (((wg >> 7) & 1) << 3);
    const int s    = (wg >> 3) & 15;
    const int tid  = threadIdx.x;
    const int wave = tid >> 6;
    const int lane = tid & 63;
    const int cg   = lane & 15;                 // col-group: cols cg*64..+63
    const int rt   = (wave << 2) + (lane >> 4); // 0..31 row-pair index
    const int row0 = s * ROWS + rt * 2;
    const int b0   = g * BPG;

    unsigned long long* hb64 = (unsigned long long*)hbuf;
    unsigned* grpcnt = &cnt[g * 32];
    unsigned sink32 = 0u;
    unsigned long long sink = 0ull;

    // ---- pre-phase: publish XCC id, group-barrier, verify same-XCD ----
    unsigned xcc;
    asm volatile("s_getreg_b32 %0, hwreg(HW_REG_XCC_ID)" : "=s"(xcc));
    xcc = (xcc & 15u) + 1u;                    // nonzero token
    if (tid == 0)
        sink32 ^= __hip_atomic_exchange(&cnt[512 + g * 16 + s], xcc,
                                        __ATOMIC_RELAXED,
                                        __HIP_MEMORY_SCOPE_AGENT);
    __syncthreads();                           // drain the exchange (vmcnt 0)
    if (tid == 0) {
        __hip_atomic_fetch_add(&cnt[g * 32 + 8], 1u, __ATOMIC_RELAXED,
                               __HIP_MEMORY_SCOPE_AGENT);
        while (__hip_atomic_fetch_add(&cnt[g * 32 + 8], 0u, __ATOMIC_RELAXED,
                                      __HIP_MEMORY_SCOPE_AGENT)
               < (unsigned)NSLICE) {
            __builtin_amdgcn_s_sleep(1);
        }
    }
    __syncthreads();
    unsigned vx = xcc;
    if (tid < NSLICE)
        vx = __hip_atomic_fetch_add(&cnt[512 + g * 16 + tid], 0u,
                                    __ATOMIC_RELAXED,
                                    __HIP_MEMORY_SCOPE_AGENT);
    const bool fastp = (__syncthreads_and((int)(vx == xcc)) != 0);

    // ---- persistent register weights: 2 rows x 16 float4 ----
    float4 w0[16], w1[16];
    {
        const float4* p0 = (const float4*)(W_res + (size_t)row0 * H_) + (cg << 4);
        const float4* p1 = (const float4*)(W_res + (size_t)(row0 + 1) * H_) + (cg << 4);
#pragma unroll
        for (int k = 0; k < 16; ++k) { w0[k] = p0[k]; w1[k] = p1[k]; }
    }

    // h tiles in LDS, padded chunks: col c of batch b at hl[b][(c/64)*66 + c%64]
    __shared__ __align__(16) float hl[BPG][16 * CHUNK];

    // h-fill role: thread loads 4 consecutive h floats (2 u64 reads)
    const int fb = tid >> 8;                 // batch 0/1
    const int fc = (tid << 2) & 1023;        // col base (multiple of 4)
    float* hlw = &hl[fb][(fc >> 6) * CHUNK + (fc & 63)];

    // finalize role: lanes cg<2 own batch b0+cg, rows (row0, row0+1)
    const bool fin  = (cg < BPG);
    const int  fbat = cg;                    // 0/1 (valid when fin)
    float* op0 = out + ((size_t)(b0 + (fin ? fbat : 0)) * H_ + row0) * (size_t)T_;
    float* op1 = op0 + T_;                   // next row, same batch

    float xp0 = fin ? op0[0] : 0.0f;         // x_proj for step 0
    float xp1 = fin ? op1[0] : 0.0f;
    float hprev0 = 0.0f, hprev1 = 0.0f;      // own rows' exact f32 state

    for (int t = 0; t < T_; ++t) {
        const int p = t & 1;

        // (A) h -> LDS. fast: TCC-coherent atomic loads; slow: RMW reads.
        {
            const size_t i64 = (((size_t)(p * B_ + b0 + fb) * H_) + fc) >> 1;
            unsigned long long q0, q1;
            if (fastp) {
                q0 = __hip_atomic_load(hb64 + i64, __ATOMIC_RELAXED,
                                       __HIP_MEMORY_SCOPE_AGENT);
                q1 = __hip_atomic_load(hb64 + i64 + 1, __ATOMIC_RELAXED,
                                       __HIP_MEMORY_SCOPE_AGENT);
            } else {
                q0 = __hip_atomic_fetch_add(hb64 + i64, 0ull, __ATOMIC_RELAXED,
                                            __HIP_MEMORY_SCOPE_AGENT);
                q1 = __hip_atomic_fetch_add(hb64 + i64 + 1, 0ull,
                                            __ATOMIC_RELAXED,
                                            __HIP_MEMORY_SCOPE_AGENT);
            }
            float4 v = make_float4(__uint_as_float((unsigned)q0),
                                   __uint_as_float((unsigned)(q0 >> 32)),
                                   __uint_as_float((unsigned)q1),
                                   __uint_as_float((unsigned)(q1 >> 32)));
            *(float4*)hlw = v;
        }
        __syncthreads();
        __builtin_amdgcn_sched_barrier(0);

        // prefetch next step's x_proj (plain cached; overlapped with the dot)
        float xp0n = 0.0f, xp1n = 0.0f;
        if (fin && t + 1 < T_) { xp0n = op0[t + 1]; xp1n = op1[t + 1]; }

        // (B) dot: 2 rows x 64 cols x 2 batches, weights from registers
        float s00 = 0.f, s01 = 0.f, s10 = 0.f, s11 = 0.f;  // s[row][batch]
        const float* h0 = &hl[0][cg * CHUNK];
        const float* h1 = &hl[1][cg * CHUNK];
#pragma unroll
        for (int k = 0; k < 16; ++k) {
            const float4 ha  = *(const float4*)(h0 + 4 * k);
            const float4 hb4 = *(const float4*)(h1 + 4 * k);
            const float4 u = w0[k], v = w1[k];
            s00 = fmaf(u.x, ha.x, s00);  s00 = fmaf(u.y, ha.y, s00);
            s00 = fmaf(u.z, ha.z, s00);  s00 = fmaf(u.w, ha.w, s00);
            s10 = fmaf(v.x, ha.x, s10);  s10 = fmaf(v.y, ha.y, s10);
            s10 = fmaf(v.z, ha.z, s10);  s10 = fmaf(v.w, ha.w, s10);
            s01 = fmaf(u.x, hb4.x, s01); s01 = fmaf(u.y, hb4.y, s01);
            s01 = fmaf(u.z, hb4.z, s01); s01 = fmaf(u.w, hb4.w, s01);
            s11 = fmaf(v.x, hb4.x, s11); s11 = fmaf(v.y, hb4.y, s11);
            s11 = fmaf(v.z, hb4.z, s11); s11 = fmaf(v.w, hb4.w, s11);
        }
        // (C) reduce over the 16 cg lanes
#pragma unroll
        for (int m = 1; m <= 8; m <<= 1) {
            s00 += __shfl_xor(s00, m);
            s01 += __shfl_xor(s01, m);
            s10 += __shfl_xor(s10, m);
            s11 += __shfl_xor(s11, m);
        }

        // (D) finalize: lane cg owns batch b0+cg, rows row0 & row0+1
        if (fin) {
            const float sA = fbat ? s01 : s00;   // row0
            const float sB = fbat ? s11 : s10;   // row0+1
            const float pre0 = tanhf(xp0 + sA);
            const float pre1 = tanhf(xp1 + sB);
            const float hn0 = fmaf(0.1f, hprev0, 0.9f * pre0);
            const float hn1 = fmaf(0.1f, hprev1, 0.9f * pre1);
            hprev0 = hn0;
            hprev1 = hn1;
            op0[t] = hn0;                         // plain cached output stores
            op1[t] = hn1;
            const unsigned long long pack =
                ((unsigned long long)__float_as_uint(hn1) << 32) |
                (unsigned long long)__float_as_uint(hn0);
            const size_t w64 =
                (((size_t)(((t + 1) & 1) * B_ + b0 + fbat) * H_) + row0) >> 1;
            // RETURNING swap: ack => executed at (local) TCC
            sink ^= __hip_atomic_exchange(hb64 + w64, pack,
                                          __ATOMIC_RELAXED,
                                          __HIP_MEMORY_SCOPE_AGENT);
        }
        xp0 = xp0n;
        xp1 = xp1n;

        // (E) group barrier: monotone counter; fast polls are atomic loads
        if (t + 1 < T_) {
            __syncthreads();   // vmcnt(0): all swaps executed at TCC
            __builtin_amdgcn_sched_barrier(0);
            if (tid == 0) {
                __hip_atomic_fetch_add(grpcnt, 1u, __ATOMIC_RELAXED,
                                       __HIP_MEMORY_SCOPE_AGENT);
                const unsigned tgt = (unsigned)NSLICE * (unsigned)(t + 1);
                for (;;) {
                    unsigned c;
                    if (fastp)
                        c = __hip_atomic_load(grpcnt, __ATOMIC_RELAXED,
                                              __HIP_MEMORY_SCOPE_AGENT);
                    else
                        c = __hip_atomic_fetch_add(grpcnt, 0u, __ATOMIC_RELAXED,
                                                   __HIP_MEMORY_SCOPE_AGENT);
                    if (c >= tgt) break;
                    __builtin_amdgcn_s_sleep(1);
                }
            }
            __syncthreads();
            __builtin_amdgcn_sched_barrier(0);
        }
    }

    // keep returning forms live
    if (((sink ^ (unsigned long long)sink32) == 0x9E3779B97F4A7C15ull) && tid == 0)
        cnt[1000] = 1u;
}

extern "C" void kernel_launch(void* const* d_in, const int* in_sizes, int n_in,
                              void* d_out, int out_size, void* d_ws, size_t ws_size,
                              hipStream_t stream) {
    const float* x     = (const float*)d_in[0];   // (B, C, T)
    const float* W_in  = (const float*)d_in[1];   // (H, C)
    const float* W_res = (const float*)d_in[2];   // (H, H)
    const float* bias  = (const float*)d_in[3];   // (H,)
    float* out = (float*)d_out;                   // (B, H, T)

    unsigned* cnt  = (unsigned*)d_ws;
    float*    hbuf = (float*)((char*)d_ws + 4096);

    esn_init_kernel<<<256, 256, 0, stream>>>(cnt, (unsigned*)hbuf);

    dim3 g1(T_ / 256, H_ / 8, B_);
    esn_xproj_kernel<<<g1, 256, 0, stream>>>(x, W_in, bias, out);

    esn_recur_kernel<<<NWG, NTHR, 0, stream>>>(W_res, out, cnt, hbuf);
}

// Round 10
// 18509.195 us; speedup vs baseline: 1.1390x; 1.0042x over previous
//
#include <hip/hip_runtime.h>
#include <math.h>

// Problem constants (fixed by the reference)
#define B_  32
#define C_  64
#define T_  2048
#define H_  1024

// Recurrence decomposition: 16 groups x 2 batches; 16 WGs (slices) per group
#define NGROUP 16
#define BPG    2
#define NSLICE 16
#define ROWS   64                    // H / NSLICE
#define NWG    (NGROUP * NSLICE)     // 256 WGs == 256 CUs, 1/CU -> co-resident
#define NTHR   512
#define CHUNK  66                    // padded LDS chunk stride (conflicts = 0)

// d_ws layout:
//   [0, 4096)          : unsigned cnt[1024]:
//                          cnt[g*32]      main barrier counter (one line/group)
//                          cnt[g*32+8]    pre-phase arrival counter
//                          cnt[512+g*16+s] published XCC id (+1) of WG (g,s)
//                          cnt[1000]      sink dump (never actually written)
//   [4096, 4096+256KB) : float hbuf[2][B_][H_] (dense ping-pong h exchange)

__global__ void esn_init_kernel(unsigned* cnt, unsigned* hbuf32) {
    int i = blockIdx.x * blockDim.x + threadIdx.x;
    if (i < 1024) cnt[i] = 0u;
    hbuf32[i] = 0u;   // grid 256x256 = 65536 = 2*B_*H_
}

// ---------------------------------------------------------------------------
// x_proj[b,h,t] = bias[h] + sum_c x[b,c,t] * W_in[h,c] -> d_out (B,H,T)
// ---------------------------------------------------------------------------
__global__ __launch_bounds__(256) void esn_xproj_kernel(
        const float* __restrict__ x,
        const float* __restrict__ W_in,
        const float* __restrict__ bias,
        float* __restrict__ out) {
    __shared__ float xs[32 * 256];
    const int tid = threadIdx.x;
    const int t0  = blockIdx.x * 256;
    const int h0  = blockIdx.y * 8;
    const int b   = blockIdx.z;
    const float* xb = x + (size_t)b * C_ * T_ + t0;

    float acc[8];
#pragma unroll
    for (int h = 0; h < 8; ++h) acc[h] = 0.0f;

    for (int ch = 0; ch < 2; ++ch) {
        for (int idx = tid; idx < 32 * 64; idx += 256) {
            const int c  = idx >> 6;
            const int t4 = idx & 63;
            float4 v = *(const float4*)(xb + (size_t)(ch * 32 + c) * T_ + t4 * 4);
            *(float4*)(&xs[c * 256 + t4 * 4]) = v;
        }
        __syncthreads();
        for (int c = 0; c < 32; ++c) {
            const float xv = xs[c * 256 + tid];
#pragma unroll
            for (int h = 0; h < 8; ++h)
                acc[h] = fmaf(xv, W_in[(size_t)(h0 + h) * C_ + ch * 32 + c], acc[h]);
        }
        __syncthreads();
    }

    float* ob = out + (size_t)b * H_ * T_ + t0 + tid;
#pragma unroll
    for (int h = 0; h < 8; ++h)
        ob[(size_t)(h0 + h) * T_] = acc[h] + bias[h0 + h];
}

// ---------------------------------------------------------------------------
// Recurrence. XCD-affinity swizzle: g=(wg&7)|((wg>>7)<<3), s=(wg>>3)&15 —
// under round-robin dispatch (wg->XCD = wg%8) every group is XCD-pure;
// pre-phase VERIFIES via HW_REG_XCC_ID. Verdict selects the h-READ path:
//   fast: relaxed agent atomic LOADS (L1-bypass; coherent with the group's
//         exchange-writes under verified same-XCD — proven round 9, FETCH ~
//         read volume, absmax clean).
//   slow: round-6 RMW(fetch_add+0) reads — correct on any topology.
// Round-10 change vs round 9 (single variable): the BARRIER POLL is back to
// RMW fetch_add(+0) in BOTH paths (round-6 proven form). Round 9's load-based
// poll against a concurrently-RMW'd counter line was the prime stall suspect
// (8.9 us/step with all pipes idle).
// h-writes stay returning-exchanges; barrier arrive stays fetch_add.
// Weights: thread (cg,rt) holds W_res[s*64+rt*2+{0,1}][cg*64..+63] in
// registers across the t-loop (no __restrict__ -> reload illegal).
// ---------------------------------------------------------------------------
__global__ __launch_bounds__(NTHR, 2) void esn_recur_kernel(
        const float* W_res,
        float* out,
        unsigned* cnt,
        float* hbuf) {
    const int wg   = blockIdx.x;
    const int g    = (wg & 7) | (((wg >> 7) & 1) << 3);
    const int s    = (wg >> 3) & 15;
    const int tid  = threadIdx.x;
    const int wave = tid >> 6;
    const int lane = tid & 63;
    const int cg   = lane & 15;                 // col-group: cols cg*64..+63
    const int rt   = (wave << 2) + (lane >> 4); // 0..31 row-pair index
    const int row0 = s * ROWS + rt * 2;
    const int b0   = g * BPG;

    unsigned long long* hb64 = (unsigned long long*)hbuf;
    unsigned* grpcnt = &cnt[g * 32];
    unsigned sink32 = 0u;
    unsigned long long sink = 0ull;

    // ---- pre-phase: publish XCC id, group-barrier, verify same-XCD ----
    unsigned xcc;
    asm volatile("s_getreg_b32 %0, hwreg(HW_REG_XCC_ID)" : "=s"(xcc));
    xcc = (xcc & 15u) + 1u;                    // nonzero token
    if (tid == 0)
        sink32 ^= __hip_atomic_exchange(&cnt[512 + g * 16 + s], xcc,
                                        __ATOMIC_RELAXED,
                                        __HIP_MEMORY_SCOPE_AGENT);
    __syncthreads();                           // drain the exchange (vmcnt 0)
    if (tid == 0) {
        __hip_atomic_fetch_add(&cnt[g * 32 + 8], 1u, __ATOMIC_RELAXED,
                               __HIP_MEMORY_SCOPE_AGENT);
        while (__hip_atomic_fetch_add(&cnt[g * 32 + 8], 0u, __ATOMIC_RELAXED,
                                      __HIP_MEMORY_SCOPE_AGENT)
               < (unsigned)NSLICE) {
            __builtin_amdgcn_s_sleep(1);
        }
    }
    __syncthreads();
    unsigned vx = xcc;
    if (tid < NSLICE)
        vx = __hip_atomic_fetch_add(&cnt[512 + g * 16 + tid], 0u,
                                    __ATOMIC_RELAXED,
                                    __HIP_MEMORY_SCOPE_AGENT);
    const bool fastp = (__syncthreads_and((int)(vx == xcc)) != 0);

    // ---- persistent register weights: 2 rows x 16 float4 ----
    float4 w0[16], w1[16];
    {
        const float4* p0 = (const float4*)(W_res + (size_t)row0 * H_) + (cg << 4);
        const float4* p1 = (const float4*)(W_res + (size_t)(row0 + 1) * H_) + (cg << 4);
#pragma unroll
        for (int k = 0; k < 16; ++k) { w0[k] = p0[k]; w1[k] = p1[k]; }
    }

    // h tiles in LDS, padded chunks: col c of batch b at hl[b][(c/64)*66 + c%64]
    __shared__ __align__(16) float hl[BPG][16 * CHUNK];

    // h-fill role: thread loads 4 consecutive h floats (2 u64 reads)
    const int fb = tid >> 8;                 // batch 0/1
    const int fc = (tid << 2) & 1023;        // col base (multiple of 4)
    float* hlw = &hl[fb][(fc >> 6) * CHUNK + (fc & 63)];

    // finalize role: lanes cg<2 own batch b0+cg, rows (row0, row0+1)
    const bool fin  = (cg < BPG);
    const int  fbat = cg;                    // 0/1 (valid when fin)
    float* op0 = out + ((size_t)(b0 + (fin ? fbat : 0)) * H_ + row0) * (size_t)T_;
    float* op1 = op0 + T_;                   // next row, same batch

    float xp0 = fin ? op0[0] : 0.0f;         // x_proj for step 0
    float xp1 = fin ? op1[0] : 0.0f;
    float hprev0 = 0.0f, hprev1 = 0.0f;      // own rows' exact f32 state

    for (int t = 0; t < T_; ++t) {
        const int p = t & 1;

        // (A) h -> LDS. fast: coherent atomic loads; slow: RMW reads.
        {
            const size_t i64 = (((size_t)(p * B_ + b0 + fb) * H_) + fc) >> 1;
            unsigned long long q0, q1;
            if (fastp) {
                q0 = __hip_atomic_load(hb64 + i64, __ATOMIC_RELAXED,
                                       __HIP_MEMORY_SCOPE_AGENT);
                q1 = __hip_atomic_load(hb64 + i64 + 1, __ATOMIC_RELAXED,
                                       __HIP_MEMORY_SCOPE_AGENT);
            } else {
                q0 = __hip_atomic_fetch_add(hb64 + i64, 0ull, __ATOMIC_RELAXED,
                                            __HIP_MEMORY_SCOPE_AGENT);
                q1 = __hip_atomic_fetch_add(hb64 + i64 + 1, 0ull,
                                            __ATOMIC_RELAXED,
                                            __HIP_MEMORY_SCOPE_AGENT);
            }
            float4 v = make_float4(__uint_as_float((unsigned)q0),
                                   __uint_as_float((unsigned)(q0 >> 32)),
                                   __uint_as_float((unsigned)q1),
                                   __uint_as_float((unsigned)(q1 >> 32)));
            *(float4*)hlw = v;
        }
        __syncthreads();
        __builtin_amdgcn_sched_barrier(0);

        // prefetch next step's x_proj (plain cached; overlapped with the dot)
        float xp0n = 0.0f, xp1n = 0.0f;
        if (fin && t + 1 < T_) { xp0n = op0[t + 1]; xp1n = op1[t + 1]; }

        // (B) dot: 2 rows x 64 cols x 2 batches, weights from registers
        float s00 = 0.f, s01 = 0.f, s10 = 0.f, s11 = 0.f;  // s[row][batch]
        const float* h0 = &hl[0][cg * CHUNK];
        const float* h1 = &hl[1][cg * CHUNK];
#pragma unroll
        for (int k = 0; k < 16; ++k) {
            const float4 ha  = *(const float4*)(h0 + 4 * k);
            const float4 hb4 = *(const float4*)(h1 + 4 * k);
            const float4 u = w0[k], v = w1[k];
            s00 = fmaf(u.x, ha.x, s00);  s00 = fmaf(u.y, ha.y, s00);
            s00 = fmaf(u.z, ha.z, s00);  s00 = fmaf(u.w, ha.w, s00);
            s10 = fmaf(v.x, ha.x, s10);  s10 = fmaf(v.y, ha.y, s10);
            s10 = fmaf(v.z, ha.z, s10);  s10 = fmaf(v.w, ha.w, s10);
            s01 = fmaf(u.x, hb4.x, s01); s01 = fmaf(u.y, hb4.y, s01);
            s01 = fmaf(u.z, hb4.z, s01); s01 = fmaf(u.w, hb4.w, s01);
            s11 = fmaf(v.x, hb4.x, s11); s11 = fmaf(v.y, hb4.y, s11);
            s11 = fmaf(v.z, hb4.z, s11); s11 = fmaf(v.w, hb4.w, s11);
        }
        // (C) reduce over the 16 cg lanes
#pragma unroll
        for (int m = 1; m <= 8; m <<= 1) {
            s00 += __shfl_xor(s00, m);
            s01 += __shfl_xor(s01, m);
            s10 += __shfl_xor(s10, m);
            s11 += __shfl_xor(s11, m);
        }

        // (D) finalize: lane cg owns batch b0+cg, rows row0 & row0+1
        if (fin) {
            const float sA = fbat ? s01 : s00;   // row0
            const float sB = fbat ? s11 : s10;   // row0+1
            const float pre0 = tanhf(xp0 + sA);
            const float pre1 = tanhf(xp1 + sB);
            const float hn0 = fmaf(0.1f, hprev0, 0.9f * pre0);
            const float hn1 = fmaf(0.1f, hprev1, 0.9f * pre1);
            hprev0 = hn0;
            hprev1 = hn1;
            op0[t] = hn0;                         // plain cached output stores
            op1[t] = hn1;
            const unsigned long long pack =
                ((unsigned long long)__float_as_uint(hn1) << 32) |
                (unsigned long long)__float_as_uint(hn0);
            const size_t w64 =
                (((size_t)(((t + 1) & 1) * B_ + b0 + fbat) * H_) + row0) >> 1;
            // RETURNING swap: ack => executed at coherence point
            sink ^= __hip_atomic_exchange(hb64 + w64, pack,
                                          __ATOMIC_RELAXED,
                                          __HIP_MEMORY_SCOPE_AGENT);
        }
        xp0 = xp0n;
        xp1 = xp1n;

        // (E) group barrier: monotone counter, ALL-RMW (round-6 proven form)
        if (t + 1 < T_) {
            __syncthreads();   // vmcnt(0): all swaps executed
            __builtin_amdgcn_sched_barrier(0);
            if (tid == 0) {
                __hip_atomic_fetch_add(grpcnt, 1u, __ATOMIC_RELAXED,
                                       __HIP_MEMORY_SCOPE_AGENT);
                const unsigned tgt = (unsigned)NSLICE * (unsigned)(t + 1);
                while (__hip_atomic_fetch_add(grpcnt, 0u, __ATOMIC_RELAXED,
                                              __HIP_MEMORY_SCOPE_AGENT) < tgt) {
                    __builtin_amdgcn_s_sleep(1);
                }
            }
            __syncthreads();
            __builtin_amdgcn_sched_barrier(0);
        }
    }

    // keep returning forms live
    if (((sink ^ (unsigned long long)sink32) == 0x9E3779B97F4A7C15ull) && tid == 0)
        cnt[1000] = 1u;
}

extern "C" void kernel_launch(void* const* d_in, const int* in_sizes, int n_in,
                              void* d_out, int out_size, void* d_ws, size_t ws_size,
                              hipStream_t stream) {
    const float* x     = (const float*)d_in[0];   // (B, C, T)
    const float* W_in  = (const float*)d_in[1];   // (H, C)
    const float* W_res = (const float*)d_in[2];   // (H, H)
    const float* bias  = (const float*)d_in[3];   // (H,)
    float* out = (float*)d_out;                   // (B, H, T)

    unsigned* cnt  = (unsigned*)d_ws;
    float*    hbuf = (float*)((char*)d_ws + 4096);

    esn_init_kernel<<<256, 256, 0, stream>>>(cnt, (unsigned*)hbuf);

    dim3 g1(T_ / 256, H_ / 8, B_);
    esn_xproj_kernel<<<g1, 256, 0, stream>>>(x, W_in, bias, out);

    esn_recur_kernel<<<NWG, NTHR, 0, stream>>>(W_res, out, cnt, hbuf);
}

// Round 12
// 18493.451 us; speedup vs baseline: 1.1399x; 1.0009x over previous
//
#include <hip/hip_runtime.h>
#include <math.h>

// Problem constants (fixed by the reference)
#define B_  32
#define C_  64
#define T_  2048
#define H_  1024

// Recurrence decomposition: 16 groups x 2 batches; 16 WGs (slices) per group
#define NGROUP 16
#define BPG    2
#define NSLICE 16
#define ROWS   64                    // H / NSLICE
#define NWG    (NGROUP * NSLICE)     // 256 WGs == 256 CUs, 1/CU -> co-resident
#define NTHR   512
#define CHUNK  66                    // padded LDS chunk stride (conflicts = 0)

// d_ws layout:
//   [0, 4096)          : unsigned cnt[1024]; group g's barrier counter at
//                        cnt[g*32] (128B apart). cnt[512] = sink dump (unused)
//   [4096, 4096+256KB) : float hbuf[2][B_][H_] (dense ping-pong h exchange)

__global__ void esn_init_kernel(unsigned* cnt, unsigned* hbuf32) {
    int i = blockIdx.x * blockDim.x + threadIdx.x;
    if (i < 1024) cnt[i] = 0u;
    hbuf32[i] = 0u;   // grid 256x256 = 65536 = 2*B_*H_
}

// ---------------------------------------------------------------------------
// x_proj[b,h,t] = bias[h] + sum_c x[b,c,t] * W_in[h,c] -> d_out (B,H,T)
// ---------------------------------------------------------------------------
__global__ __launch_bounds__(256) void esn_xproj_kernel(
        const float* __restrict__ x,
        const float* __restrict__ W_in,
        const float* __restrict__ bias,
        float* __restrict__ out) {
    __shared__ float xs[32 * 256];
    const int tid = threadIdx.x;
    const int t0  = blockIdx.x * 256;
    const int h0  = blockIdx.y * 8;
    const int b   = blockIdx.z;
    const float* xb = x + (size_t)b * C_ * T_ + t0;

    float acc[8];
#pragma unroll
    for (int h = 0; h < 8; ++h) acc[h] = 0.0f;

    for (int ch = 0; ch < 2; ++ch) {
        for (int idx = tid; idx < 32 * 64; idx += 256) {
            const int c  = idx >> 6;
            const int t4 = idx & 63;
            float4 v = *(const float4*)(xb + (size_t)(ch * 32 + c) * T_ + t4 * 4);
            *(float4*)(&xs[c * 256 + t4 * 4]) = v;
        }
        __syncthreads();
        for (int c = 0; c < 32; ++c) {
            const float xv = xs[c * 256 + tid];
#pragma unroll
            for (int h = 0; h < 8; ++h)
                acc[h] = fmaf(xv, W_in[(size_t)(h0 + h) * C_ + ch * 32 + c], acc[h]);
        }
        __syncthreads();
    }

    float* ob = out + (size_t)b * H_ * T_ + t0 + tid;
#pragma unroll
    for (int h = 0; h < 8; ++h)
        ob[(size_t)(h0 + h) * T_] = acc[h] + bias[h0 + h];
}

// ---------------------------------------------------------------------------
// Recurrence = round-6 protocol (ALL cross-WG traffic via relaxed AGENT-scope
// atomic RMWs; topology-agnostic, proven 3.23us/step) + round-9 XCD-pure
// swizzle g=(wg&7)|((wg>>7)<<3), s=(wg>>3)&15 (proven: FETCH collapse +
// verdict pass). Under round-robin dispatch all 16 WGs of a group sit on one
// XCD, so their RMWs execute in ONE TCC: the hbuf/counter lines never
// migrate across the fabric (round 6 paid ~5 migrations/line/step, the
// dominant cost; rounds 9-11 showed loads are worse, WG-scope is deadlock).
// If the dispatch mapping ever changes this degrades to round-6 perf, not
// correctness.
//   h read  : u64 fetch_add(+0) x2 per thread (reads the coherent copy)
//   h write : returning u64 exchange per row pair (ack=executed at TCC)
//   barrier : monotone per-group agent-RMW counter (arrive after
//             __syncthreads vmcnt(0) drain; tid0 polls fetch_add(+0))
// Weights: thread (cg,rt) holds W_res[s*64+rt*2+{0,1}][cg*64..+63] in
// registers across the t-loop (no __restrict__ -> in-loop reload illegal
// under possible aliasing with the stores).
// ---------------------------------------------------------------------------
__global__ __launch_bounds__(NTHR, 2) void esn_recur_kernel(
        const float* W_res,
        float* out,
        unsigned* cnt,
        float* hbuf) {
    const int wg   = blockIdx.x;
    const int g    = (wg & 7) | (((wg >> 7) & 1) << 3);
    const int s    = (wg >> 3) & 15;
    const int tid  = threadIdx.x;
    const int wave = tid >> 6;
    const int lane = tid & 63;
    const int cg   = lane & 15;                 // col-group: cols cg*64..+63
    const int rt   = (wave << 2) + (lane >> 4); // 0..31 row-pair index
    const int row0 = s * ROWS + rt * 2;
    const int b0   = g * BPG;

    unsigned long long* hb64 = (unsigned long long*)hbuf;
    unsigned* grpcnt = &cnt[g * 32];
    unsigned long long sink = 0ull;

    // ---- persistent register weights: 2 rows x 16 float4 ----
    float4 w0[16], w1[16];
    {
        const float4* p0 = (const float4*)(W_res + (size_t)row0 * H_) + (cg << 4);
        const float4* p1 = (const float4*)(W_res + (size_t)(row0 + 1) * H_) + (cg << 4);
#pragma unroll
        for (int k = 0; k < 16; ++k) { w0[k] = p0[k]; w1[k] = p1[k]; }
    }

    // h tiles in LDS, padded chunks: col c of batch b at hl[b][(c/64)*66 + c%64]
    __shared__ __align__(16) float hl[BPG][16 * CHUNK];

    // h-fill role: thread loads 4 consecutive h floats (2 u64 RMWs)
    const int fb = tid >> 8;                 // batch 0/1
    const int fc = (tid << 2) & 1023;        // col base (multiple of 4)
    float* hlw = &hl[fb][(fc >> 6) * CHUNK + (fc & 63)];

    // finalize role: lanes cg<2 own batch b0+cg, rows (row0, row0+1)
    const bool fin  = (cg < BPG);
    const int  fbat = cg;                    // 0/1 (valid when fin)
    float* op0 = out + ((size_t)(b0 + (fin ? fbat : 0)) * H_ + row0) * (size_t)T_;
    float* op1 = op0 + T_;                   // next row, same batch

    float xp0 = fin ? op0[0] : 0.0f;         // x_proj for step 0
    float xp1 = fin ? op1[0] : 0.0f;
    float hprev0 = 0.0f, hprev1 = 0.0f;      // own rows' exact f32 state

    for (int t = 0; t < T_; ++t) {
        const int p = t & 1;

        // (A) h -> LDS via u64 fetch_add(+0), executed in the (local) TCC
        {
            const size_t i64 = (((size_t)(p * B_ + b0 + fb) * H_) + fc) >> 1;
            unsigned long long q0 = __hip_atomic_fetch_add(
                hb64 + i64, 0ull, __ATOMIC_RELAXED, __HIP_MEMORY_SCOPE_AGENT);
            unsigned long long q1 = __hip_atomic_fetch_add(
                hb64 + i64 + 1, 0ull, __ATOMIC_RELAXED, __HIP_MEMORY_SCOPE_AGENT);
            float4 v = make_float4(__uint_as_float((unsigned)q0),
                                   __uint_as_float((unsigned)(q0 >> 32)),
                                   __uint_as_float((unsigned)q1),
                                   __uint_as_float((unsigned)(q1 >> 32)));
            *(float4*)hlw = v;
        }
        __syncthreads();
        __builtin_amdgcn_sched_barrier(0);

        // prefetch next step's x_proj (plain cached; overlapped with the dot)
        float xp0n = 0.0f, xp1n = 0.0f;
        if (fin && t + 1 < T_) { xp0n = op0[t + 1]; xp1n = op1[t + 1]; }

        // (B) dot: 2 rows x 64 cols x 2 batches, weights from registers
        float s00 = 0.f, s01 = 0.f, s10 = 0.f, s11 = 0.f;  // s[row][batch]
        const float* h0 = &hl[0][cg * CHUNK];
        const float* h1 = &hl[1][cg * CHUNK];
#pragma unroll
        for (int k = 0; k < 16; ++k) {
            const float4 ha  = *(const float4*)(h0 + 4 * k);
            const float4 hb4 = *(const float4*)(h1 + 4 * k);
            const float4 u = w0[k], v = w1[k];
            s00 = fmaf(u.x, ha.x, s00);  s00 = fmaf(u.y, ha.y, s00);
            s00 = fmaf(u.z, ha.z, s00);  s00 = fmaf(u.w, ha.w, s00);
            s10 = fmaf(v.x, ha.x, s10);  s10 = fmaf(v.y, ha.y, s10);
            s10 = fmaf(v.z, ha.z, s10);  s10 = fmaf(v.w, ha.w, s10);
            s01 = fmaf(u.x, hb4.x, s01); s01 = fmaf(u.y, hb4.y, s01);
            s01 = fmaf(u.z, hb4.z, s01); s01 = fmaf(u.w, hb4.w, s01);
            s11 = fmaf(v.x, hb4.x, s11); s11 = fmaf(v.y, hb4.y, s11);
            s11 = fmaf(v.z, hb4.z, s11); s11 = fmaf(v.w, hb4.w, s11);
        }
        // (C) reduce over the 16 cg lanes
#pragma unroll
        for (int m = 1; m <= 8; m <<= 1) {
            s00 += __shfl_xor(s00, m);
            s01 += __shfl_xor(s01, m);
            s10 += __shfl_xor(s10, m);
            s11 += __shfl_xor(s11, m);
        }

        // (D) finalize: lane cg owns batch b0+cg, rows row0 & row0+1
        if (fin) {
            const float sA = fbat ? s01 : s00;   // row0
            const float sB = fbat ? s11 : s10;   // row0+1
            const float pre0 = tanhf(xp0 + sA);
            const float pre1 = tanhf(xp1 + sB);
            const float hn0 = fmaf(0.1f, hprev0, 0.9f * pre0);
            const float hn1 = fmaf(0.1f, hprev1, 0.9f * pre1);
            hprev0 = hn0;
            hprev1 = hn1;
            op0[t] = hn0;                         // plain cached output stores
            op1[t] = hn1;
            const unsigned long long pack =
                ((unsigned long long)__float_as_uint(hn1) << 32) |
                (unsigned long long)__float_as_uint(hn0);
            const size_t w64 =
                (((size_t)(((t + 1) & 1) * B_ + b0 + fbat) * H_) + row0) >> 1;
            // RETURNING swap: ack => executed at the coherence point
            sink ^= __hip_atomic_exchange(hb64 + w64, pack,
                                          __ATOMIC_RELAXED,
                                          __HIP_MEMORY_SCOPE_AGENT);
        }
        xp0 = xp0n;
        xp1 = xp1n;

        // (E) group barrier: monotone agent-RMW counter (round-6 proven)
        if (t + 1 < T_) {
            __syncthreads();   // vmcnt(0): all swaps executed
            __builtin_amdgcn_sched_barrier(0);
            if (tid == 0) {
                __hip_atomic_fetch_add(grpcnt, 1u, __ATOMIC_RELAXED,
                                       __HIP_MEMORY_SCOPE_AGENT);
                const unsigned tgt = (unsigned)NSLICE * (unsigned)(t + 1);
                while (__hip_atomic_fetch_add(grpcnt, 0u, __ATOMIC_RELAXED,
                                              __HIP_MEMORY_SCOPE_AGENT) < tgt) {
                    __builtin_amdgcn_s_sleep(1);
                }
            }
            __syncthreads();
            __builtin_amdgcn_sched_barrier(0);
        }
    }

    // keep the swap returns live (forces the returning/sc0 form)
    if (sink == 0x9E3779B97F4A7C15ull && tid == 0) cnt[512] = 1u;
}

extern "C" void kernel_launch(void* const* d_in, const int* in_sizes, int n_in,
                              void* d_out, int out_size, void* d_ws, size_t ws_size,
                              hipStream_t stream) {
    const float* x     = (const float*)d_in[0];   // (B, C, T)
    const float* W_in  = (const float*)d_in[1];   // (H, C)
    const float* W_res = (const float*)d_in[2];   // (H, H)
    const float* bias  = (const float*)d_in[3];   // (H,)
    float* out = (float*)d_out;                   // (B, H, T)

    unsigned* cnt  = (unsigned*)d_ws;
    float*    hbuf = (float*)((char*)d_ws + 4096);

    esn_init_kernel<<<256, 256, 0, stream>>>(cnt, (unsigned*)hbuf);

    dim3 g1(T_ / 256, H_ / 8, B_);
    esn_xproj_kernel<<<g1, 256, 0, stream>>>(x, W_in, bias, out);

    esn_recur_kernel<<<NWG, NTHR, 0, stream>>>(W_res, out, cnt, hbuf);
}